// Round 3
// baseline (1282.770 us; speedup 1.0000x reference)
//
#include <hip/hip_runtime.h>
#include <hip/hip_bf16.h>

#define NGRAPHS 512

typedef __attribute__((ext_vector_type(8))) short bf16x8;
typedef __attribute__((ext_vector_type(4))) float f32x4;

__device__ inline short f2bf(float x) {
    __hip_bfloat16 h = __float2bfloat16(x);
    return *(short*)&h;
}

// ---------------- CSR build ----------------

__global__ void k_hist(const int* __restrict__ dst, int* __restrict__ counts, int nE) {
    int e = blockIdx.x * blockDim.x + threadIdx.x;
    if (e < nE) atomicAdd(&counts[dst[e]], 1);
}

__global__ void k_scan_block(const int* __restrict__ counts, int* __restrict__ incl,
                             int* __restrict__ blockSums, int n) {
    __shared__ int s[256];
    int t = threadIdx.x;
    int idx = blockIdx.x * 256 + t;
    int v = (idx < n) ? counts[idx] : 0;
    s[t] = v;
    __syncthreads();
    for (int off = 1; off < 256; off <<= 1) {
        int x = (t >= off) ? s[t - off] : 0;
        __syncthreads();
        s[t] += x;
        __syncthreads();
    }
    if (idx < n) incl[idx] = s[t];
    if (t == 255) blockSums[blockIdx.x] = s[255];
}

__global__ void k_scan_sums(const int* __restrict__ blockSums, int* __restrict__ blockOffs, int nb) {
    __shared__ int s[512];
    int t = threadIdx.x;
    int v = (t < nb) ? blockSums[t] : 0;
    s[t] = v;
    __syncthreads();
    for (int off = 1; off < 512; off <<= 1) {
        int x = (t >= off) ? s[t - off] : 0;
        __syncthreads();
        s[t] += x;
        __syncthreads();
    }
    if (t < nb) blockOffs[t] = s[t] - v;  // exclusive
}

__global__ void k_finish_csr(const int* __restrict__ counts, const int* __restrict__ incl,
                             const int* __restrict__ blockOffs, int* __restrict__ row_start,
                             int* __restrict__ cursor, float* __restrict__ rdeg, int n, int nE) {
    int i = blockIdx.x * blockDim.x + threadIdx.x;
    if (i < n) {
        int ex = incl[i] - counts[i] + blockOffs[i >> 8];
        row_start[i] = ex;
        cursor[i] = ex;
        int d = counts[i] > 1 ? counts[i] : 1;
        rdeg[i] = 1.0f / (float)d;
    }
    if (i == 0) row_start[n] = nE;
}

__global__ void k_scatter(const int* __restrict__ src, const int* __restrict__ dst,
                          int* __restrict__ cursor, int* __restrict__ col, int nE) {
    int e = blockIdx.x * blockDim.x + threadIdx.x;
    if (e < nE) {
        int p = atomicAdd(&cursor[dst[e]], 1);
        col[p] = src[e];
    }
}

// ---------------- f32 -> bf16 cast ----------------

__global__ __launch_bounds__(256) void k_cast(const float* __restrict__ x,
                                              ushort* __restrict__ xb, int total4) {
    int i = blockIdx.x * 256 + threadIdx.x;
    if (i >= total4) return;
    float4 v = ((const float4*)x)[i];
    ushort4 o;
    o.x = (ushort)f2bf(v.x);
    o.y = (ushort)f2bf(v.y);
    o.z = (ushort)f2bf(v.z);
    o.w = (ushort)f2bf(v.w);
    ((ushort4*)xb)[i] = o;
}

// ---------------- mean aggregation over CSR, bf16 in/out ----------------
// one wave per node; lane covers 2 channels (uint = 2 bf16), 256B/row transaction.

__global__ __launch_bounds__(256) void k_agg(const ushort* __restrict__ h,
                                             const int* __restrict__ row_start,
                                             const int* __restrict__ col,
                                             const float* __restrict__ rdeg,
                                             ushort* __restrict__ out, int n) {
    int w = (blockIdx.x * blockDim.x + threadIdx.x) >> 6;
    int lane = threadIdx.x & 63;
    if (w >= n) return;
    int s = row_start[w], e = row_start[w + 1];
    float a0 = 0.f, a1 = 0.f;
    int j = s;
    for (; j + 1 < e; j += 2) {
        int c0 = col[j], c1 = col[j + 1];
        uint v0 = *(const uint*)(h + (size_t)c0 * 128 + lane * 2);
        uint v1 = *(const uint*)(h + (size_t)c1 * 128 + lane * 2);
        a0 += __uint_as_float(v0 << 16) + __uint_as_float(v1 << 16);
        a1 += __uint_as_float(v0 & 0xffff0000u) + __uint_as_float(v1 & 0xffff0000u);
    }
    if (j < e) {
        uint v0 = *(const uint*)(h + (size_t)col[j] * 128 + lane * 2);
        a0 += __uint_as_float(v0 << 16);
        a1 += __uint_as_float(v0 & 0xffff0000u);
    }
    float r = rdeg[w];
    ushort2 o;
    o.x = (ushort)f2bf(a0 * r);
    o.y = (ushort)f2bf(a1 * r);
    *(ushort2*)(out + (size_t)w * 128 + lane * 2) = o;
}

// ---------------- weight prep: split f32 W into bf16 hi+lo, [OUTC][256] ----------------

__global__ void k_wprep(const float* __restrict__ wn, const float* __restrict__ ws,
                        short* __restrict__ whi, short* __restrict__ wlo, int outc) {
    int i = blockIdx.x * 256 + threadIdx.x;
    if (i >= outc * 256) return;
    int c = i >> 8, k = i & 255;
    float w = (k < 128) ? wn[c * 128 + k] : ws[c * 128 + k - 128];
    short hi = f2bf(w);
    __hip_bfloat16 hb = *(__hip_bfloat16*)&hi;
    float hif = __bfloat162float(hb);
    whi[i] = hi;
    wlo[i] = f2bf(w - hif);
}

// ---------------- MFMA transform: out = [mean|h] @ [Wn;Ws]^T + b   (bf16 in/out) ----------------

template <int OUTC, bool RELU, int CHUNK>
__global__ __launch_bounds__(256, 2) void k_transform_mfma(
    const ushort* __restrict__ meanbuf, const ushort* __restrict__ hbuf,
    const bf16x8* __restrict__ whi, const bf16x8* __restrict__ wlo,
    const float* __restrict__ bias, ushort* __restrict__ out, int n) {
    constexpr int NCF = OUTC / 64;  // colfrags per wave: 128->2, 64->1
    const int wave = threadIdx.x >> 6;
    const int lane = threadIdx.x & 63;
    const int lmod = lane & 15, lgrp = lane >> 4;
    const int n0 = wave * (NCF * 16);

    // B fragments: lane holds W[c = n0+cf*16+lmod][k = 32*ks+8*lgrp+e]
    bf16x8 bh[NCF][8], bl[NCF][8];
#pragma unroll
    for (int cf = 0; cf < NCF; ++cf) {
        int c = n0 + cf * 16 + lmod;
#pragma unroll
        for (int ks = 0; ks < 8; ++ks) {
            int idx = c * 32 + ks * 4 + lgrp;
            bh[cf][ks] = whi[idx];
            bl[cf][ks] = wlo[idx];
        }
    }

    const int tile0 = blockIdx.x * CHUNK;
    for (int t = 0; t < CHUNK; ++t) {
        int row0 = (tile0 + t) * 16;
        if (row0 >= n) break;
        int m = row0 + lmod;
        const ushort* mrow = meanbuf + (size_t)m * 128;
        const ushort* hrow = hbuf + (size_t)m * 128;

        // A fragments: lane holds Acat[m][k = 32*ks+8*lgrp+e]; direct 16B bf16 loads
        bf16x8 af[8];
#pragma unroll
        for (int ks = 0; ks < 4; ++ks) af[ks] = *(const bf16x8*)(mrow + ks * 32 + lgrp * 8);
#pragma unroll
        for (int ks = 0; ks < 4; ++ks) af[4 + ks] = *(const bf16x8*)(hrow + ks * 32 + lgrp * 8);

        f32x4 acc[NCF];
#pragma unroll
        for (int cf = 0; cf < NCF; ++cf) acc[cf] = (f32x4){0.f, 0.f, 0.f, 0.f};
#pragma unroll
        for (int ks = 0; ks < 8; ++ks) {
#pragma unroll
            for (int cf = 0; cf < NCF; ++cf) {
                acc[cf] = __builtin_amdgcn_mfma_f32_16x16x32_bf16(af[ks], bh[cf][ks], acc[cf], 0, 0, 0);
                acc[cf] = __builtin_amdgcn_mfma_f32_16x16x32_bf16(af[ks], bl[cf][ks], acc[cf], 0, 0, 0);
            }
        }

        // epilogue: D[row = row0 + lgrp*4 + r][col = n0 + cf*16 + lmod]
#pragma unroll
        for (int cf = 0; cf < NCF; ++cf) {
            int c = n0 + cf * 16 + lmod;
            float bv = bias[c];
#pragma unroll
            for (int r = 0; r < 4; ++r) {
                int rr = row0 + lgrp * 4 + r;
                float v = acc[cf][r] + bv;
                if (RELU) v = fmaxf(v, 0.f);
                out[(size_t)rr * OUTC + c] = (ushort)f2bf(v);
            }
        }
    }
}

// ---------------- pool: binary-search graph bounds, then per-graph block reduce ----------------

__global__ void k_gbounds(const int* __restrict__ batch, int* __restrict__ gstart, int n) {
    int g = blockIdx.x * blockDim.x + threadIdx.x;
    if (g > NGRAPHS) return;
    int lo = 0, hi = n;
    while (lo < hi) {
        int mid = (lo + hi) >> 1;
        if (batch[mid] < g) lo = mid + 1; else hi = mid;
    }
    gstart[g] = lo;
}

__global__ __launch_bounds__(256) void k_pool2(const ushort* __restrict__ h,
                                               const int* __restrict__ gstart,
                                               float* __restrict__ out) {
    int g = blockIdx.x;
    int t = threadIdx.x, lane = t & 63, wv = t >> 6;
    int s = gstart[g], e = gstart[g + 1];
    float acc = 0.f;
    for (int i = s + wv; i < e; i += 4) {
        uint v = h[(size_t)i * 64 + lane];
        acc += __uint_as_float(v << 16);
    }
    __shared__ float red[4][64];
    red[wv][lane] = acc;
    __syncthreads();
    if (wv == 0) {
        float tot = red[0][lane] + red[1][lane] + red[2][lane] + red[3][lane];
        float c = (float)(e - s);
        out[g * 64 + lane] = tot / fmaxf(c, 1.0f);
    }
}

// ---------------- launcher ----------------

extern "C" void kernel_launch(void* const* d_in, const int* in_sizes, int n_in,
                              void* d_out, int out_size, void* d_ws, size_t ws_size,
                              hipStream_t stream) {
    const float* x = (const float*)d_in[0];
    const int* ei = (const int*)d_in[1];
    const int* batch = (const int*)d_in[2];
    const float* wn0 = (const float*)d_in[3];
    const float* ws0 = (const float*)d_in[4];
    const float* b0 = (const float*)d_in[5];
    const float* wn1 = (const float*)d_in[6];
    const float* ws1 = (const float*)d_in[7];
    const float* b1 = (const float*)d_in[8];
    const float* wn2 = (const float*)d_in[9];
    const float* ws2 = (const float*)d_in[10];
    const float* b2 = (const float*)d_in[11];

    const int n = in_sizes[0] / 128;  // 100000
    const int nE = in_sizes[1] / 2;   // 1600000
    const int* src = ei;
    const int* dst = ei + nE;

    char* p = (char*)d_ws;
    auto alloc = [&](size_t bytes) {
        void* r = (void*)p;
        p += (bytes + 255) & ~(size_t)255;
        return r;
    };
    int* counts = (int*)alloc((size_t)n * 4);
    int* incl = (int*)alloc((size_t)n * 4);
    int* blockSums = (int*)alloc(4096);
    int* blockOffs = (int*)alloc(4096);
    int* row_start = (int*)alloc((size_t)(n + 1) * 4);
    int* cursor = (int*)alloc((size_t)n * 4);
    float* rdeg = (float*)alloc((size_t)n * 4);
    int* col = (int*)alloc((size_t)nE * 4);
    int* gstart = (int*)alloc((size_t)(NGRAPHS + 1) * 4);
    short* whi0 = (short*)alloc(128 * 256 * 2);
    short* wlo0 = (short*)alloc(128 * 256 * 2);
    short* whi1 = (short*)alloc(128 * 256 * 2);
    short* wlo1 = (short*)alloc(128 * 256 * 2);
    short* whi2 = (short*)alloc(64 * 256 * 2);
    short* wlo2 = (short*)alloc(64 * 256 * 2);
    ushort* xb = (ushort*)alloc((size_t)n * 128 * 2);
    ushort* meanb = (ushort*)alloc((size_t)n * 128 * 2);
    ushort* h1 = (ushort*)alloc((size_t)n * 128 * 2);
    ushort* h2 = (ushort*)alloc((size_t)n * 128 * 2);
    ushort* h3 = (ushort*)alloc((size_t)n * 64 * 2);

    hipMemsetAsync(counts, 0, (size_t)n * 4, stream);

    const int tb = 256;
    const int nb = (n + 255) / 256;

    k_hist<<<(nE + tb - 1) / tb, tb, 0, stream>>>(dst, counts, nE);
    k_scan_block<<<nb, 256, 0, stream>>>(counts, incl, blockSums, n);
    k_scan_sums<<<1, 512, 0, stream>>>(blockSums, blockOffs, nb);
    k_finish_csr<<<nb, 256, 0, stream>>>(counts, incl, blockOffs, row_start, cursor, rdeg, n, nE);
    k_scatter<<<(nE + tb - 1) / tb, tb, 0, stream>>>(src, dst, cursor, col, nE);

    k_cast<<<((n * 128 / 4) + 255) / 256, 256, 0, stream>>>(x, xb, n * 128 / 4);

    k_wprep<<<(128 * 256 + 255) / 256, 256, 0, stream>>>(wn0, ws0, whi0, wlo0, 128);
    k_wprep<<<(128 * 256 + 255) / 256, 256, 0, stream>>>(wn1, ws1, whi1, wlo1, 128);
    k_wprep<<<(64 * 256 + 255) / 256, 256, 0, stream>>>(wn2, ws2, whi2, wlo2, 64);

    k_gbounds<<<3, 256, 0, stream>>>(batch, gstart, n);

    const int aggGrid = ((n * 64) + tb - 1) / tb;
    const int nTiles = (n + 15) / 16;          // 6250
    const int CH = 13;
    const int tGrid = (nTiles + CH - 1) / CH;  // 481

    // layer 0
    k_agg<<<aggGrid, tb, 0, stream>>>(xb, row_start, col, rdeg, meanb, n);
    k_transform_mfma<128, true, 13><<<tGrid, 256, 0, stream>>>(
        meanb, xb, (const bf16x8*)whi0, (const bf16x8*)wlo0, b0, h1, n);
    // layer 1
    k_agg<<<aggGrid, tb, 0, stream>>>(h1, row_start, col, rdeg, meanb, n);
    k_transform_mfma<128, true, 13><<<tGrid, 256, 0, stream>>>(
        meanb, h1, (const bf16x8*)whi1, (const bf16x8*)wlo1, b1, h2, n);
    // layer 2
    k_agg<<<aggGrid, tb, 0, stream>>>(h2, row_start, col, rdeg, meanb, n);
    k_transform_mfma<64, false, 13><<<tGrid, 256, 0, stream>>>(
        meanb, h2, (const bf16x8*)whi2, (const bf16x8*)wlo2, b2, h3, n);

    // pool -> d_out
    k_pool2<<<NGRAPHS, 256, 0, stream>>>(h3, gstart, (float*)d_out);
}

// Round 5
// 404.649 us; speedup vs baseline: 3.1701x; 3.1701x over previous
//
#include <hip/hip_runtime.h>
#include <hip/hip_bf16.h>

#define NGRAPHS 512
#define BCAP 8192

typedef __attribute__((ext_vector_type(8))) short bf16x8;
typedef __attribute__((ext_vector_type(4))) float f32x4;

__device__ inline short f2bf(float x) {
    __hip_bfloat16 h = __float2bfloat16(x);
    return *(short*)&h;
}

// ---------------- bucket-sort CSR build ----------------
// bucket b = dst >> 8 (256 nodes/bucket), fixed-capacity regions, padded CSR.

__global__ __launch_bounds__(256) void k_bscatter(const int* __restrict__ src,
                                                  const int* __restrict__ dst,
                                                  int* __restrict__ bcur,
                                                  uint* __restrict__ pairs,
                                                  int nE, int NB) {
    __shared__ int cnt[512];
    __shared__ int gbase[512];
    const int t = threadIdx.x;
    const int seg0 = blockIdx.x * 4096;

    for (int l = t; l < NB; l += 256) cnt[l] = 0;
    __syncthreads();

    int sv[16], bv[16], rv[16];
#pragma unroll
    for (int k = 0; k < 16; ++k) {
        int e = seg0 + k * 256 + t;
        if (e < nE) {
            int d = dst[e];
            bv[k] = d >> 8;
            rv[k] = atomicAdd(&cnt[bv[k]], 1);
            sv[k] = src[e] | ((d & 255) << 20);
        } else {
            bv[k] = -1;
        }
    }
    __syncthreads();
    for (int l = t; l < NB; l += 256) {
        int c = cnt[l];
        gbase[l] = (c > 0) ? atomicAdd(&bcur[l], c) : 0;
    }
    __syncthreads();
#pragma unroll
    for (int k = 0; k < 16; ++k) {
        if (bv[k] >= 0) {
            int pos = gbase[bv[k]] + rv[k];
            if (pos < BCAP) pairs[(size_t)bv[k] * BCAP + pos] = (uint)sv[k];
        }
    }
}

__global__ __launch_bounds__(256) void k_bbuild(const int* __restrict__ bcur,
                                                const uint* __restrict__ pairs,
                                                int* __restrict__ row_start,
                                                int* __restrict__ row_end,
                                                float* __restrict__ rdeg,
                                                int* __restrict__ col, int n) {
    __shared__ int s[256];
    __shared__ int cur[256];
    const int b = blockIdx.x;
    const int t = threadIdx.x;
    const uint* bp = pairs + (size_t)b * BCAP;
    int cnt = bcur[b];
    if (cnt > BCAP) cnt = BCAP;

    s[t] = 0;
    __syncthreads();
    for (int i = t; i < cnt; i += 256) {
        int local = bp[i] >> 20;
        atomicAdd(&s[local], 1);
    }
    __syncthreads();
    int my = s[t];
    for (int off = 1; off < 256; off <<= 1) {
        int v = (t >= off) ? s[t - off] : 0;
        __syncthreads();
        s[t] += v;
        __syncthreads();
    }
    int excl = s[t] - my;
    int v = b * 256 + t;
    if (v < n) {
        row_start[v] = b * BCAP + excl;
        row_end[v] = b * BCAP + excl + my;
        rdeg[v] = 1.0f / (float)(my > 1 ? my : 1);
    }
    cur[t] = excl;
    __syncthreads();
    for (int i = t; i < cnt; i += 256) {
        uint u = bp[i];
        int local = u >> 20;
        int pos = atomicAdd(&cur[local], 1);
        col[(size_t)b * BCAP + pos] = (int)(u & 0xFFFFFu);
    }
}

// ---------------- f32 -> bf16 cast ----------------

__global__ __launch_bounds__(256) void k_cast(const float* __restrict__ x,
                                              ushort* __restrict__ xb, int total4) {
    int i = blockIdx.x * 256 + threadIdx.x;
    if (i >= total4) return;
    float4 v = ((const float4*)x)[i];
    ushort4 o;
    o.x = (ushort)f2bf(v.x);
    o.y = (ushort)f2bf(v.y);
    o.z = (ushort)f2bf(v.z);
    o.w = (ushort)f2bf(v.w);
    ((ushort4*)xb)[i] = o;
}

// ---------------- mean aggregation over padded CSR, bf16 in/out ----------------
// one wave per node; lane covers 2 channels; 4 independent row loads in flight.

__global__ __launch_bounds__(256) void k_agg(const ushort* __restrict__ h,
                                             const int* __restrict__ row_start,
                                             const int* __restrict__ row_end,
                                             const int* __restrict__ col,
                                             const float* __restrict__ rdeg,
                                             ushort* __restrict__ out, int n) {
    int w = (blockIdx.x * blockDim.x + threadIdx.x) >> 6;
    int lane = threadIdx.x & 63;
    if (w >= n) return;
    int s = row_start[w], e = row_end[w];
    float a0 = 0.f, a1 = 0.f;
    int j = s;
    for (; j + 3 < e; j += 4) {
        int c0 = col[j], c1 = col[j + 1], c2 = col[j + 2], c3 = col[j + 3];
        uint v0 = *(const uint*)(h + (size_t)c0 * 128 + lane * 2);
        uint v1 = *(const uint*)(h + (size_t)c1 * 128 + lane * 2);
        uint v2 = *(const uint*)(h + (size_t)c2 * 128 + lane * 2);
        uint v3 = *(const uint*)(h + (size_t)c3 * 128 + lane * 2);
        a0 += __uint_as_float(v0 << 16) + __uint_as_float(v1 << 16) +
              __uint_as_float(v2 << 16) + __uint_as_float(v3 << 16);
        a1 += __uint_as_float(v0 & 0xffff0000u) + __uint_as_float(v1 & 0xffff0000u) +
              __uint_as_float(v2 & 0xffff0000u) + __uint_as_float(v3 & 0xffff0000u);
    }
    for (; j < e; ++j) {
        uint v0 = *(const uint*)(h + (size_t)col[j] * 128 + lane * 2);
        a0 += __uint_as_float(v0 << 16);
        a1 += __uint_as_float(v0 & 0xffff0000u);
    }
    float r = rdeg[w];
    ushort2 o;
    o.x = (ushort)f2bf(a0 * r);
    o.y = (ushort)f2bf(a1 * r);
    *(ushort2*)(out + (size_t)w * 128 + lane * 2) = o;
}

// ---------------- weight prep: split f32 W into bf16 hi+lo, [OUTC][256] ----------------

__global__ void k_wprep(const float* __restrict__ wn, const float* __restrict__ ws,
                        short* __restrict__ whi, short* __restrict__ wlo, int outc) {
    int i = blockIdx.x * 256 + threadIdx.x;
    if (i >= outc * 256) return;
    int c = i >> 8, k = i & 255;
    float w = (k < 128) ? wn[c * 128 + k] : ws[c * 128 + k - 128];
    short hi = f2bf(w);
    __hip_bfloat16 hb = *(__hip_bfloat16*)&hi;
    float hif = __bfloat162float(hb);
    whi[i] = hi;
    wlo[i] = f2bf(w - hif);
}

// ---------------- MFMA transform: out = [mean|h] @ [Wn;Ws]^T + b  (bf16 in/out) ----------------

template <int OUTC, bool RELU, int CHUNK>
__global__ __launch_bounds__(256, 2) void k_transform_mfma(
    const ushort* __restrict__ meanbuf, const ushort* __restrict__ hbuf,
    const bf16x8* __restrict__ whi, const bf16x8* __restrict__ wlo,
    const float* __restrict__ bias, ushort* __restrict__ out, int n) {
    constexpr int NCF = OUTC / 64;
    const int wave = threadIdx.x >> 6;
    const int lane = threadIdx.x & 63;
    const int lmod = lane & 15, lgrp = lane >> 4;
    const int n0 = wave * (NCF * 16);

    bf16x8 bh[NCF][8], bl[NCF][8];
#pragma unroll
    for (int cf = 0; cf < NCF; ++cf) {
        int c = n0 + cf * 16 + lmod;
#pragma unroll
        for (int ks = 0; ks < 8; ++ks) {
            int idx = c * 32 + ks * 4 + lgrp;
            bh[cf][ks] = whi[idx];
            bl[cf][ks] = wlo[idx];
        }
    }

    const int tile0 = blockIdx.x * CHUNK;
    for (int t = 0; t < CHUNK; ++t) {
        int row0 = (tile0 + t) * 16;
        if (row0 >= n) break;
        int m = row0 + lmod;
        const ushort* mrow = meanbuf + (size_t)m * 128;
        const ushort* hrow = hbuf + (size_t)m * 128;

        bf16x8 af[8];
#pragma unroll
        for (int ks = 0; ks < 4; ++ks) af[ks] = *(const bf16x8*)(mrow + ks * 32 + lgrp * 8);
#pragma unroll
        for (int ks = 0; ks < 4; ++ks) af[4 + ks] = *(const bf16x8*)(hrow + ks * 32 + lgrp * 8);

        f32x4 acc[NCF];
#pragma unroll
        for (int cf = 0; cf < NCF; ++cf) acc[cf] = (f32x4){0.f, 0.f, 0.f, 0.f};
#pragma unroll
        for (int ks = 0; ks < 8; ++ks) {
#pragma unroll
            for (int cf = 0; cf < NCF; ++cf) {
                acc[cf] = __builtin_amdgcn_mfma_f32_16x16x32_bf16(af[ks], bh[cf][ks], acc[cf], 0, 0, 0);
                acc[cf] = __builtin_amdgcn_mfma_f32_16x16x32_bf16(af[ks], bl[cf][ks], acc[cf], 0, 0, 0);
            }
        }

#pragma unroll
        for (int cf = 0; cf < NCF; ++cf) {
            int c = n0 + cf * 16 + lmod;
            float bv = bias[c];
#pragma unroll
            for (int r = 0; r < 4; ++r) {
                int rr = row0 + lgrp * 4 + r;
                float v = acc[cf][r] + bv;
                if (RELU) v = fmaxf(v, 0.f);
                out[(size_t)rr * OUTC + c] = (ushort)f2bf(v);
            }
        }
    }
}

// ---------------- pool ----------------

__global__ void k_gbounds(const int* __restrict__ batch, int* __restrict__ gstart, int n) {
    int g = blockIdx.x * blockDim.x + threadIdx.x;
    if (g > NGRAPHS) return;
    int lo = 0, hi = n;
    while (lo < hi) {
        int mid = (lo + hi) >> 1;
        if (batch[mid] < g) lo = mid + 1; else hi = mid;
    }
    gstart[g] = lo;
}

__global__ __launch_bounds__(256) void k_pool2(const ushort* __restrict__ h,
                                               const int* __restrict__ gstart,
                                               float* __restrict__ out) {
    int g = blockIdx.x;
    int t = threadIdx.x, lane = t & 63, wv = t >> 6;
    int s = gstart[g], e = gstart[g + 1];
    float acc = 0.f;
    for (int i = s + wv; i < e; i += 4) {
        uint v = h[(size_t)i * 64 + lane];
        acc += __uint_as_float(v << 16);
    }
    __shared__ float red[4][64];
    red[wv][lane] = acc;
    __syncthreads();
    if (wv == 0) {
        float tot = red[0][lane] + red[1][lane] + red[2][lane] + red[3][lane];
        float c = (float)(e - s);
        out[g * 64 + lane] = tot / fmaxf(c, 1.0f);
    }
}

// ---------------- launcher ----------------

extern "C" void kernel_launch(void* const* d_in, const int* in_sizes, int n_in,
                              void* d_out, int out_size, void* d_ws, size_t ws_size,
                              hipStream_t stream) {
    const float* x = (const float*)d_in[0];
    const int* ei = (const int*)d_in[1];
    const int* batch = (const int*)d_in[2];
    const float* wn0 = (const float*)d_in[3];
    const float* ws0 = (const float*)d_in[4];
    const float* b0 = (const float*)d_in[5];
    const float* wn1 = (const float*)d_in[6];
    const float* ws1 = (const float*)d_in[7];
    const float* b1 = (const float*)d_in[8];
    const float* wn2 = (const float*)d_in[9];
    const float* ws2 = (const float*)d_in[10];
    const float* b2 = (const float*)d_in[11];

    const int n = in_sizes[0] / 128;  // 100000
    const int nE = in_sizes[1] / 2;   // 1600000
    const int* src = ei;
    const int* dst = ei + nE;
    const int NB = (n + 255) >> 8;    // 391 buckets

    char* p = (char*)d_ws;
    auto alloc = [&](size_t bytes) {
        void* r = (void*)p;
        p += (bytes + 255) & ~(size_t)255;
        return r;
    };
    int* bcur = (int*)alloc((size_t)NB * 4);
    uint* pairs = (uint*)alloc((size_t)NB * BCAP * 4);
    int* col = (int*)alloc((size_t)NB * BCAP * 4);
    int* row_start = (int*)alloc((size_t)NB * 256 * 4);
    int* row_end = (int*)alloc((size_t)NB * 256 * 4);
    float* rdeg = (float*)alloc((size_t)NB * 256 * 4);
    int* gstart = (int*)alloc((size_t)(NGRAPHS + 1) * 4);
    short* whi0 = (short*)alloc(128 * 256 * 2);
    short* wlo0 = (short*)alloc(128 * 256 * 2);
    short* whi1 = (short*)alloc(128 * 256 * 2);
    short* wlo1 = (short*)alloc(128 * 256 * 2);
    short* whi2 = (short*)alloc(64 * 256 * 2);
    short* wlo2 = (short*)alloc(64 * 256 * 2);
    ushort* xb = (ushort*)alloc((size_t)n * 128 * 2);
    ushort* meanb = (ushort*)alloc((size_t)n * 128 * 2);
    ushort* h1 = (ushort*)alloc((size_t)n * 128 * 2);
    ushort* h2 = (ushort*)alloc((size_t)n * 128 * 2);
    ushort* h3 = (ushort*)alloc((size_t)n * 64 * 2);

    (void)hipMemsetAsync(bcur, 0, (size_t)NB * 4, stream);

    const int tb = 256;

    k_bscatter<<<(nE + 4095) / 4096, tb, 0, stream>>>(src, dst, bcur, pairs, nE, NB);
    k_bbuild<<<NB, tb, 0, stream>>>(bcur, pairs, row_start, row_end, rdeg, col, n);

    k_cast<<<((n * 128 / 4) + 255) / 256, 256, 0, stream>>>(x, xb, n * 128 / 4);

    k_wprep<<<(128 * 256 + 255) / 256, 256, 0, stream>>>(wn0, ws0, whi0, wlo0, 128);
    k_wprep<<<(128 * 256 + 255) / 256, 256, 0, stream>>>(wn1, ws1, whi1, wlo1, 128);
    k_wprep<<<(64 * 256 + 255) / 256, 256, 0, stream>>>(wn2, ws2, whi2, wlo2, 64);

    k_gbounds<<<3, 256, 0, stream>>>(batch, gstart, n);

    const int aggGrid = ((n * 64) + tb - 1) / tb;
    const int nTiles = (n + 15) / 16;
    const int CH = 13;
    const int tGrid = (nTiles + CH - 1) / CH;

    // layer 0
    k_agg<<<aggGrid, tb, 0, stream>>>(xb, row_start, row_end, col, rdeg, meanb, n);
    k_transform_mfma<128, true, 13><<<tGrid, 256, 0, stream>>>(
        meanb, xb, (const bf16x8*)whi0, (const bf16x8*)wlo0, b0, h1, n);
    // layer 1
    k_agg<<<aggGrid, tb, 0, stream>>>(h1, row_start, row_end, col, rdeg, meanb, n);
    k_transform_mfma<128, true, 13><<<tGrid, 256, 0, stream>>>(
        meanb, h1, (const bf16x8*)whi1, (const bf16x8*)wlo1, b1, h2, n);
    // layer 2
    k_agg<<<aggGrid, tb, 0, stream>>>(h2, row_start, row_end, col, rdeg, meanb, n);
    k_transform_mfma<64, false, 13><<<tGrid, 256, 0, stream>>>(
        meanb, h2, (const bf16x8*)whi2, (const bf16x8*)wlo2, b2, h3, n);

    // pool -> d_out
    k_pool2<<<NGRAPHS, 256, 0, stream>>>(h3, gstart, (float*)d_out);
}

// Round 6
// 375.846 us; speedup vs baseline: 3.4130x; 1.0766x over previous
//
#include <hip/hip_runtime.h>
#include <hip/hip_bf16.h>

#define NGRAPHS 512
#define BCAP 8192

typedef __attribute__((ext_vector_type(8))) short bf16x8;
typedef __attribute__((ext_vector_type(4))) float f32x4;

__device__ inline short f2bf(float x) {
    __hip_bfloat16 h = __float2bfloat16(x);
    return *(short*)&h;
}

// ---------------- bucket-sort CSR build ----------------
// bucket b = dst >> 8 (256 nodes/bucket), fixed-capacity regions, padded CSR.

__global__ __launch_bounds__(256) void k_bscatter(const int* __restrict__ src,
                                                  const int* __restrict__ dst,
                                                  int* __restrict__ bcur,
                                                  uint* __restrict__ pairs,
                                                  int nE, int NB) {
    __shared__ int cnt[512];
    __shared__ int gbase[512];
    const int t = threadIdx.x;
    const int seg0 = blockIdx.x * 4096;

    for (int l = t; l < NB; l += 256) cnt[l] = 0;
    __syncthreads();

    int sv[16], bv[16], rv[16];
#pragma unroll
    for (int k = 0; k < 16; ++k) {
        int e = seg0 + k * 256 + t;
        if (e < nE) {
            int d = dst[e];
            bv[k] = d >> 8;
            rv[k] = atomicAdd(&cnt[bv[k]], 1);
            sv[k] = src[e] | ((d & 255) << 20);
        } else {
            bv[k] = -1;
        }
    }
    __syncthreads();
    for (int l = t; l < NB; l += 256) {
        int c = cnt[l];
        gbase[l] = (c > 0) ? atomicAdd(&bcur[l], c) : 0;
    }
    __syncthreads();
#pragma unroll
    for (int k = 0; k < 16; ++k) {
        if (bv[k] >= 0) {
            int pos = gbase[bv[k]] + rv[k];
            if (pos < BCAP) pairs[(size_t)bv[k] * BCAP + pos] = (uint)sv[k];
        }
    }
}

__global__ __launch_bounds__(256) void k_bbuild(const int* __restrict__ bcur,
                                                const uint* __restrict__ pairs,
                                                int* __restrict__ row_start,
                                                int* __restrict__ row_end,
                                                float* __restrict__ rdeg,
                                                int* __restrict__ col, int n) {
    __shared__ int s[256];
    __shared__ int cur[256];
    const int b = blockIdx.x;
    const int t = threadIdx.x;
    const uint* bp = pairs + (size_t)b * BCAP;
    int cnt = bcur[b];
    if (cnt > BCAP) cnt = BCAP;

    s[t] = 0;
    __syncthreads();
    for (int i = t; i < cnt; i += 256) {
        int local = bp[i] >> 20;
        atomicAdd(&s[local], 1);
    }
    __syncthreads();
    int my = s[t];
    for (int off = 1; off < 256; off <<= 1) {
        int v = (t >= off) ? s[t - off] : 0;
        __syncthreads();
        s[t] += v;
        __syncthreads();
    }
    int excl = s[t] - my;
    int v = b * 256 + t;
    if (v < n) {
        row_start[v] = b * BCAP + excl;
        row_end[v] = b * BCAP + excl + my;
        rdeg[v] = 1.0f / (float)(my > 1 ? my : 1);
    }
    cur[t] = excl;
    __syncthreads();
    for (int i = t; i < cnt; i += 256) {
        uint u = bp[i];
        int local = u >> 20;
        int pos = atomicAdd(&cur[local], 1);
        col[(size_t)b * BCAP + pos] = (int)(u & 0xFFFFFu);
    }
}

// ---------------- f32 -> bf16 cast ----------------

__global__ __launch_bounds__(256) void k_cast(const float* __restrict__ x,
                                              ushort* __restrict__ xb, int total4) {
    int i = blockIdx.x * 256 + threadIdx.x;
    if (i >= total4) return;
    float4 v = ((const float4*)x)[i];
    ushort4 o;
    o.x = (ushort)f2bf(v.x);
    o.y = (ushort)f2bf(v.y);
    o.z = (ushort)f2bf(v.z);
    o.w = (ushort)f2bf(v.w);
    ((ushort4*)xb)[i] = o;
}

// ---------------- mean aggregation over padded CSR, bf16 in/out ----------------
// one wave per node. 4 edges per load instruction: grp=lane>>4 picks the edge,
// cl=lane&15 covers 8 channels (uint4 = 16B). Unroll 2 -> 8 edges (2KB) in flight.
// Cross-group butterfly (xor 16, 32) reduces the 4 partial sums at the end.

__global__ __launch_bounds__(256) void k_agg(const ushort* __restrict__ h,
                                             const int* __restrict__ row_start,
                                             const int* __restrict__ row_end,
                                             const int* __restrict__ col,
                                             const float* __restrict__ rdeg,
                                             ushort* __restrict__ out, int n) {
    int w = (blockIdx.x * blockDim.x + threadIdx.x) >> 6;
    int lane = threadIdx.x & 63;
    if (w >= n) return;
    int s = row_start[w], e = row_end[w];
    int grp = lane >> 4;
    int cl = lane & 15;

    float a0 = 0.f, a1 = 0.f, a2 = 0.f, a3 = 0.f, a4 = 0.f, a5 = 0.f, a6 = 0.f, a7 = 0.f;

    if (e > s) {
        int cfirst = col[s];
        for (int j = s; j < e; j += 8) {
            int j0 = j + grp, j1 = j + 4 + grp;
            bool ok0 = j0 < e, ok1 = j1 < e;
            int c0 = ok0 ? col[j0] : cfirst;
            int c1 = ok1 ? col[j1] : cfirst;
            uint4 r0 = *(const uint4*)(h + (size_t)c0 * 128 + cl * 8);
            uint4 r1 = *(const uint4*)(h + (size_t)c1 * 128 + cl * 8);
            if (ok0) {
                a0 += __uint_as_float(r0.x << 16); a1 += __uint_as_float(r0.x & 0xffff0000u);
                a2 += __uint_as_float(r0.y << 16); a3 += __uint_as_float(r0.y & 0xffff0000u);
                a4 += __uint_as_float(r0.z << 16); a5 += __uint_as_float(r0.z & 0xffff0000u);
                a6 += __uint_as_float(r0.w << 16); a7 += __uint_as_float(r0.w & 0xffff0000u);
            }
            if (ok1) {
                a0 += __uint_as_float(r1.x << 16); a1 += __uint_as_float(r1.x & 0xffff0000u);
                a2 += __uint_as_float(r1.y << 16); a3 += __uint_as_float(r1.y & 0xffff0000u);
                a4 += __uint_as_float(r1.z << 16); a5 += __uint_as_float(r1.z & 0xffff0000u);
                a6 += __uint_as_float(r1.w << 16); a7 += __uint_as_float(r1.w & 0xffff0000u);
            }
        }
        // reduce across the 4 edge-groups
        a0 += __shfl_xor(a0, 16); a1 += __shfl_xor(a1, 16);
        a2 += __shfl_xor(a2, 16); a3 += __shfl_xor(a3, 16);
        a4 += __shfl_xor(a4, 16); a5 += __shfl_xor(a5, 16);
        a6 += __shfl_xor(a6, 16); a7 += __shfl_xor(a7, 16);
        a0 += __shfl_xor(a0, 32); a1 += __shfl_xor(a1, 32);
        a2 += __shfl_xor(a2, 32); a3 += __shfl_xor(a3, 32);
        a4 += __shfl_xor(a4, 32); a5 += __shfl_xor(a5, 32);
        a6 += __shfl_xor(a6, 32); a7 += __shfl_xor(a7, 32);
    }

    if (grp == 0) {
        float r = rdeg[w];
        uint4 o;
        o.x = (uint)(ushort)f2bf(a0 * r) | ((uint)(ushort)f2bf(a1 * r) << 16);
        o.y = (uint)(ushort)f2bf(a2 * r) | ((uint)(ushort)f2bf(a3 * r) << 16);
        o.z = (uint)(ushort)f2bf(a4 * r) | ((uint)(ushort)f2bf(a5 * r) << 16);
        o.w = (uint)(ushort)f2bf(a6 * r) | ((uint)(ushort)f2bf(a7 * r) << 16);
        *(uint4*)(out + (size_t)w * 128 + cl * 8) = o;
    }
}

// ---------------- weight prep: split f32 W into bf16 hi+lo, [OUTC][256] ----------------

__global__ void k_wprep(const float* __restrict__ wn, const float* __restrict__ ws,
                        short* __restrict__ whi, short* __restrict__ wlo, int outc) {
    int i = blockIdx.x * 256 + threadIdx.x;
    if (i >= outc * 256) return;
    int c = i >> 8, k = i & 255;
    float w = (k < 128) ? wn[c * 128 + k] : ws[c * 128 + k - 128];
    short hi = f2bf(w);
    __hip_bfloat16 hb = *(__hip_bfloat16*)&hi;
    float hif = __bfloat162float(hb);
    whi[i] = hi;
    wlo[i] = f2bf(w - hif);
}

// ---------------- MFMA transform: out = [mean|h] @ [Wn;Ws]^T + b  (bf16 in/out) ----------------

template <int OUTC, bool RELU, int CHUNK>
__global__ __launch_bounds__(256, 2) void k_transform_mfma(
    const ushort* __restrict__ meanbuf, const ushort* __restrict__ hbuf,
    const bf16x8* __restrict__ whi, const bf16x8* __restrict__ wlo,
    const float* __restrict__ bias, ushort* __restrict__ out, int n) {
    constexpr int NCF = OUTC / 64;
    const int wave = threadIdx.x >> 6;
    const int lane = threadIdx.x & 63;
    const int lmod = lane & 15, lgrp = lane >> 4;
    const int n0 = wave * (NCF * 16);

    bf16x8 bh[NCF][8], bl[NCF][8];
#pragma unroll
    for (int cf = 0; cf < NCF; ++cf) {
        int c = n0 + cf * 16 + lmod;
#pragma unroll
        for (int ks = 0; ks < 8; ++ks) {
            int idx = c * 32 + ks * 4 + lgrp;
            bh[cf][ks] = whi[idx];
            bl[cf][ks] = wlo[idx];
        }
    }

    const int tile0 = blockIdx.x * CHUNK;
    for (int t = 0; t < CHUNK; ++t) {
        int row0 = (tile0 + t) * 16;
        if (row0 >= n) break;
        int m = row0 + lmod;
        const ushort* mrow = meanbuf + (size_t)m * 128;
        const ushort* hrow = hbuf + (size_t)m * 128;

        bf16x8 af[8];
#pragma unroll
        for (int ks = 0; ks < 4; ++ks) af[ks] = *(const bf16x8*)(mrow + ks * 32 + lgrp * 8);
#pragma unroll
        for (int ks = 0; ks < 4; ++ks) af[4 + ks] = *(const bf16x8*)(hrow + ks * 32 + lgrp * 8);

        f32x4 acc[NCF];
#pragma unroll
        for (int cf = 0; cf < NCF; ++cf) acc[cf] = (f32x4){0.f, 0.f, 0.f, 0.f};
#pragma unroll
        for (int ks = 0; ks < 8; ++ks) {
#pragma unroll
            for (int cf = 0; cf < NCF; ++cf) {
                acc[cf] = __builtin_amdgcn_mfma_f32_16x16x32_bf16(af[ks], bh[cf][ks], acc[cf], 0, 0, 0);
                acc[cf] = __builtin_amdgcn_mfma_f32_16x16x32_bf16(af[ks], bl[cf][ks], acc[cf], 0, 0, 0);
            }
        }

#pragma unroll
        for (int cf = 0; cf < NCF; ++cf) {
            int c = n0 + cf * 16 + lmod;
            float bv = bias[c];
#pragma unroll
            for (int r = 0; r < 4; ++r) {
                int rr = row0 + lgrp * 4 + r;
                float v = acc[cf][r] + bv;
                if (RELU) v = fmaxf(v, 0.f);
                out[(size_t)rr * OUTC + c] = (ushort)f2bf(v);
            }
        }
    }
}

// ---------------- pool ----------------

__global__ void k_gbounds(const int* __restrict__ batch, int* __restrict__ gstart, int n) {
    int g = blockIdx.x * blockDim.x + threadIdx.x;
    if (g > NGRAPHS) return;
    int lo = 0, hi = n;
    while (lo < hi) {
        int mid = (lo + hi) >> 1;
        if (batch[mid] < g) lo = mid + 1; else hi = mid;
    }
    gstart[g] = lo;
}

__global__ __launch_bounds__(256) void k_pool2(const ushort* __restrict__ h,
                                               const int* __restrict__ gstart,
                                               float* __restrict__ out) {
    int g = blockIdx.x;
    int t = threadIdx.x, lane = t & 63, wv = t >> 6;
    int s = gstart[g], e = gstart[g + 1];
    float acc = 0.f;
    for (int i = s + wv; i < e; i += 4) {
        uint v = h[(size_t)i * 64 + lane];
        acc += __uint_as_float(v << 16);
    }
    __shared__ float red[4][64];
    red[wv][lane] = acc;
    __syncthreads();
    if (wv == 0) {
        float tot = red[0][lane] + red[1][lane] + red[2][lane] + red[3][lane];
        float c = (float)(e - s);
        out[g * 64 + lane] = tot / fmaxf(c, 1.0f);
    }
}

// ---------------- launcher ----------------

extern "C" void kernel_launch(void* const* d_in, const int* in_sizes, int n_in,
                              void* d_out, int out_size, void* d_ws, size_t ws_size,
                              hipStream_t stream) {
    const float* x = (const float*)d_in[0];
    const int* ei = (const int*)d_in[1];
    const int* batch = (const int*)d_in[2];
    const float* wn0 = (const float*)d_in[3];
    const float* ws0 = (const float*)d_in[4];
    const float* b0 = (const float*)d_in[5];
    const float* wn1 = (const float*)d_in[6];
    const float* ws1 = (const float*)d_in[7];
    const float* b1 = (const float*)d_in[8];
    const float* wn2 = (const float*)d_in[9];
    const float* ws2 = (const float*)d_in[10];
    const float* b2 = (const float*)d_in[11];

    const int n = in_sizes[0] / 128;  // 100000
    const int nE = in_sizes[1] / 2;   // 1600000
    const int* src = ei;
    const int* dst = ei + nE;
    const int NB = (n + 255) >> 8;    // 391 buckets

    char* p = (char*)d_ws;
    auto alloc = [&](size_t bytes) {
        void* r = (void*)p;
        p += (bytes + 255) & ~(size_t)255;
        return r;
    };
    int* bcur = (int*)alloc((size_t)NB * 4);
    uint* pairs = (uint*)alloc((size_t)NB * BCAP * 4);
    int* col = (int*)alloc((size_t)NB * BCAP * 4);
    int* row_start = (int*)alloc((size_t)NB * 256 * 4);
    int* row_end = (int*)alloc((size_t)NB * 256 * 4);
    float* rdeg = (float*)alloc((size_t)NB * 256 * 4);
    int* gstart = (int*)alloc((size_t)(NGRAPHS + 1) * 4);
    short* whi0 = (short*)alloc(128 * 256 * 2);
    short* wlo0 = (short*)alloc(128 * 256 * 2);
    short* whi1 = (short*)alloc(128 * 256 * 2);
    short* wlo1 = (short*)alloc(128 * 256 * 2);
    short* whi2 = (short*)alloc(64 * 256 * 2);
    short* wlo2 = (short*)alloc(64 * 256 * 2);
    ushort* xb = (ushort*)alloc((size_t)n * 128 * 2);
    ushort* meanb = (ushort*)alloc((size_t)n * 128 * 2);
    ushort* h1 = (ushort*)alloc((size_t)n * 128 * 2);
    ushort* h2 = (ushort*)alloc((size_t)n * 128 * 2);
    ushort* h3 = (ushort*)alloc((size_t)n * 64 * 2);

    (void)hipMemsetAsync(bcur, 0, (size_t)NB * 4, stream);

    const int tb = 256;

    k_bscatter<<<(nE + 4095) / 4096, tb, 0, stream>>>(src, dst, bcur, pairs, nE, NB);
    k_bbuild<<<NB, tb, 0, stream>>>(bcur, pairs, row_start, row_end, rdeg, col, n);

    k_cast<<<((n * 128 / 4) + 255) / 256, 256, 0, stream>>>(x, xb, n * 128 / 4);

    k_wprep<<<(128 * 256 + 255) / 256, 256, 0, stream>>>(wn0, ws0, whi0, wlo0, 128);
    k_wprep<<<(128 * 256 + 255) / 256, 256, 0, stream>>>(wn1, ws1, whi1, wlo1, 128);
    k_wprep<<<(64 * 256 + 255) / 256, 256, 0, stream>>>(wn2, ws2, whi2, wlo2, 64);

    k_gbounds<<<3, 256, 0, stream>>>(batch, gstart, n);

    const int aggGrid = ((n * 64) + tb - 1) / tb;
    const int nTiles = (n + 15) / 16;
    const int CH = 13;
    const int tGrid = (nTiles + CH - 1) / CH;

    // layer 0
    k_agg<<<aggGrid, tb, 0, stream>>>(xb, row_start, row_end, col, rdeg, meanb, n);
    k_transform_mfma<128, true, 13><<<tGrid, 256, 0, stream>>>(
        meanb, xb, (const bf16x8*)whi0, (const bf16x8*)wlo0, b0, h1, n);
    // layer 1
    k_agg<<<aggGrid, tb, 0, stream>>>(h1, row_start, row_end, col, rdeg, meanb, n);
    k_transform_mfma<128, true, 13><<<tGrid, 256, 0, stream>>>(
        meanb, h1, (const bf16x8*)whi1, (const bf16x8*)wlo1, b1, h2, n);
    // layer 2
    k_agg<<<aggGrid, tb, 0, stream>>>(h2, row_start, row_end, col, rdeg, meanb, n);
    k_transform_mfma<64, false, 13><<<tGrid, 256, 0, stream>>>(
        meanb, h2, (const bf16x8*)whi2, (const bf16x8*)wlo2, b2, h3, n);

    // pool -> d_out
    k_pool2<<<NGRAPHS, 256, 0, stream>>>(h3, gstart, (float*)d_out);
}

// Round 7
// 359.523 us; speedup vs baseline: 3.5680x; 1.0454x over previous
//
#include <hip/hip_runtime.h>
#include <hip/hip_bf16.h>

#define NGRAPHS 512
#define BCAP 8192

typedef __attribute__((ext_vector_type(8))) short bf16x8;
typedef __attribute__((ext_vector_type(4))) float f32x4;

__device__ inline short f2bf(float x) {
    __hip_bfloat16 h = __float2bfloat16(x);
    return *(short*)&h;
}
__device__ inline float bflo(uint v) { return __uint_as_float(v << 16); }
__device__ inline float bfhi(uint v) { return __uint_as_float(v & 0xffff0000u); }

// ---------------- bucket-sort CSR build ----------------

__global__ __launch_bounds__(256) void k_bscatter(const int* __restrict__ src,
                                                  const int* __restrict__ dst,
                                                  int* __restrict__ bcur,
                                                  uint* __restrict__ pairs,
                                                  int nE, int NB) {
    __shared__ int cnt[512];
    __shared__ int gbase[512];
    const int t = threadIdx.x;
    const int seg0 = blockIdx.x * 4096;

    for (int l = t; l < NB; l += 256) cnt[l] = 0;
    __syncthreads();

    int sv[16], bv[16], rv[16];
#pragma unroll
    for (int k = 0; k < 16; ++k) {
        int e = seg0 + k * 256 + t;
        if (e < nE) {
            int d = dst[e];
            bv[k] = d >> 8;
            rv[k] = atomicAdd(&cnt[bv[k]], 1);
            sv[k] = src[e] | ((d & 255) << 20);
        } else {
            bv[k] = -1;
        }
    }
    __syncthreads();
    for (int l = t; l < NB; l += 256) {
        int c = cnt[l];
        gbase[l] = (c > 0) ? atomicAdd(&bcur[l], c) : 0;
    }
    __syncthreads();
#pragma unroll
    for (int k = 0; k < 16; ++k) {
        if (bv[k] >= 0) {
            int pos = gbase[bv[k]] + rv[k];
            if (pos < BCAP) pairs[(size_t)bv[k] * BCAP + pos] = (uint)sv[k];
        }
    }
}

__global__ __launch_bounds__(256) void k_bbuild(const int* __restrict__ bcur,
                                                const uint* __restrict__ pairs,
                                                int* __restrict__ row_start,
                                                int* __restrict__ row_end,
                                                float* __restrict__ rdeg,
                                                int* __restrict__ col, int n) {
    __shared__ int s[256];
    __shared__ int cur[256];
    const int b = blockIdx.x;
    const int t = threadIdx.x;
    const uint* bp = pairs + (size_t)b * BCAP;
    int cnt = bcur[b];
    if (cnt > BCAP) cnt = BCAP;

    s[t] = 0;
    __syncthreads();
    for (int i = t; i < cnt; i += 256) {
        int local = bp[i] >> 20;
        atomicAdd(&s[local], 1);
    }
    __syncthreads();
    int my = s[t];
    for (int off = 1; off < 256; off <<= 1) {
        int v = (t >= off) ? s[t - off] : 0;
        __syncthreads();
        s[t] += v;
        __syncthreads();
    }
    int excl = s[t] - my;
    int v = b * 256 + t;
    if (v < n) {
        row_start[v] = b * BCAP + excl;
        row_end[v] = b * BCAP + excl + my;
        rdeg[v] = 1.0f / (float)(my > 1 ? my : 1);
    }
    cur[t] = excl;
    __syncthreads();
    for (int i = t; i < cnt; i += 256) {
        uint u = bp[i];
        int local = u >> 20;
        int pos = atomicAdd(&cur[local], 1);
        col[(size_t)b * BCAP + pos] = (int)(u & 0xFFFFFu);
    }
}

// ---------------- f32 -> bf16 cast ----------------

__global__ __launch_bounds__(256) void k_cast(const float* __restrict__ x,
                                              ushort* __restrict__ xb, int total4) {
    int i = blockIdx.x * 256 + threadIdx.x;
    if (i >= total4) return;
    float4 v = ((const float4*)x)[i];
    ushort4 o;
    o.x = (ushort)f2bf(v.x);
    o.y = (ushort)f2bf(v.y);
    o.z = (ushort)f2bf(v.z);
    o.w = (ushort)f2bf(v.w);
    ((ushort4*)xb)[i] = o;
}

// ---------------- mean aggregation (128 ch) ----------------
// one wave/node; grp=lane>>4 picks 1 of 4 edges, cl=lane&15 covers 8 ch (uint4).

__global__ __launch_bounds__(256) void k_agg(const ushort* __restrict__ h,
                                             const int* __restrict__ row_start,
                                             const int* __restrict__ row_end,
                                             const int* __restrict__ col,
                                             const float* __restrict__ rdeg,
                                             ushort* __restrict__ out, int n) {
    int w = (blockIdx.x * blockDim.x + threadIdx.x) >> 6;
    int lane = threadIdx.x & 63;
    if (w >= n) return;
    int s = row_start[w], e = row_end[w];
    int grp = lane >> 4;
    int cl = lane & 15;

    float a0 = 0.f, a1 = 0.f, a2 = 0.f, a3 = 0.f, a4 = 0.f, a5 = 0.f, a6 = 0.f, a7 = 0.f;

    if (e > s) {
        int cfirst = col[s];
        for (int j = s; j < e; j += 8) {
            int j0 = j + grp, j1 = j + 4 + grp;
            bool ok0 = j0 < e, ok1 = j1 < e;
            int c0 = ok0 ? col[j0] : cfirst;
            int c1 = ok1 ? col[j1] : cfirst;
            uint4 r0 = *(const uint4*)(h + (size_t)c0 * 128 + cl * 8);
            uint4 r1 = *(const uint4*)(h + (size_t)c1 * 128 + cl * 8);
            if (ok0) {
                a0 += bflo(r0.x); a1 += bfhi(r0.x);
                a2 += bflo(r0.y); a3 += bfhi(r0.y);
                a4 += bflo(r0.z); a5 += bfhi(r0.z);
                a6 += bflo(r0.w); a7 += bfhi(r0.w);
            }
            if (ok1) {
                a0 += bflo(r1.x); a1 += bfhi(r1.x);
                a2 += bflo(r1.y); a3 += bfhi(r1.y);
                a4 += bflo(r1.z); a5 += bfhi(r1.z);
                a6 += bflo(r1.w); a7 += bfhi(r1.w);
            }
        }
        a0 += __shfl_xor(a0, 16); a1 += __shfl_xor(a1, 16);
        a2 += __shfl_xor(a2, 16); a3 += __shfl_xor(a3, 16);
        a4 += __shfl_xor(a4, 16); a5 += __shfl_xor(a5, 16);
        a6 += __shfl_xor(a6, 16); a7 += __shfl_xor(a7, 16);
        a0 += __shfl_xor(a0, 32); a1 += __shfl_xor(a1, 32);
        a2 += __shfl_xor(a2, 32); a3 += __shfl_xor(a3, 32);
        a4 += __shfl_xor(a4, 32); a5 += __shfl_xor(a5, 32);
        a6 += __shfl_xor(a6, 32); a7 += __shfl_xor(a7, 32);
    }

    if (grp == 0) {
        float r = rdeg[w];
        uint4 o;
        o.x = (uint)(ushort)f2bf(a0 * r) | ((uint)(ushort)f2bf(a1 * r) << 16);
        o.y = (uint)(ushort)f2bf(a2 * r) | ((uint)(ushort)f2bf(a3 * r) << 16);
        o.z = (uint)(ushort)f2bf(a4 * r) | ((uint)(ushort)f2bf(a5 * r) << 16);
        o.w = (uint)(ushort)f2bf(a6 * r) | ((uint)(ushort)f2bf(a7 * r) << 16);
        *(uint4*)(out + (size_t)w * 128 + cl * 8) = o;
    }
}

// ---------------- layer-2 aggregation on t2 = [tn|ts] (64+64 ch) ----------------
// h3 = mean(tn) + ts  (bias already folded into ts). Gathers 128 B rows.

__global__ __launch_bounds__(256) void k_agg2(const ushort* __restrict__ t2,
                                              const int* __restrict__ row_start,
                                              const int* __restrict__ row_end,
                                              const int* __restrict__ col,
                                              const float* __restrict__ rdeg,
                                              ushort* __restrict__ out, int n) {
    int w = (blockIdx.x * blockDim.x + threadIdx.x) >> 6;
    int lane = threadIdx.x & 63;
    if (w >= n) return;
    int s = row_start[w], e = row_end[w];
    int grp = lane >> 4;
    int cl = lane & 15;

    float a0 = 0.f, a1 = 0.f, a2 = 0.f, a3 = 0.f;

    if (e > s) {
        int cfirst = col[s];
        for (int j = s; j < e; j += 8) {
            int j0 = j + grp, j1 = j + 4 + grp;
            bool ok0 = j0 < e, ok1 = j1 < e;
            int c0 = ok0 ? col[j0] : cfirst;
            int c1 = ok1 ? col[j1] : cfirst;
            uint2 r0 = *(const uint2*)(t2 + (size_t)c0 * 128 + cl * 4);
            uint2 r1 = *(const uint2*)(t2 + (size_t)c1 * 128 + cl * 4);
            if (ok0) {
                a0 += bflo(r0.x); a1 += bfhi(r0.x);
                a2 += bflo(r0.y); a3 += bfhi(r0.y);
            }
            if (ok1) {
                a0 += bflo(r1.x); a1 += bfhi(r1.x);
                a2 += bflo(r1.y); a3 += bfhi(r1.y);
            }
        }
        a0 += __shfl_xor(a0, 16); a1 += __shfl_xor(a1, 16);
        a2 += __shfl_xor(a2, 16); a3 += __shfl_xor(a3, 16);
        a0 += __shfl_xor(a0, 32); a1 += __shfl_xor(a1, 32);
        a2 += __shfl_xor(a2, 32); a3 += __shfl_xor(a3, 32);
    }

    if (grp == 0) {
        float r = rdeg[w];
        uint2 tsv = *(const uint2*)(t2 + (size_t)w * 128 + 64 + cl * 4);
        float t0 = bflo(tsv.x), t1 = bfhi(tsv.x);
        float t2v = bflo(tsv.y), t3 = bfhi(tsv.y);
        uint2 o;
        o.x = (uint)(ushort)f2bf(a0 * r + t0) | ((uint)(ushort)f2bf(a1 * r + t1) << 16);
        o.y = (uint)(ushort)f2bf(a2 * r + t2v) | ((uint)(ushort)f2bf(a3 * r + t3) << 16);
        *(uint2*)(out + (size_t)w * 64 + cl * 4) = o;
    }
}

// ---------------- weight prep ----------------
// layers 0/1: [128 c][256 k] = [Wn|Ws] hi+lo
__global__ void k_wprep(const float* __restrict__ wn, const float* __restrict__ ws,
                        short* __restrict__ whi, short* __restrict__ wlo, int outc) {
    int i = blockIdx.x * 256 + threadIdx.x;
    if (i >= outc * 256) return;
    int c = i >> 8, k = i & 255;
    float w = (k < 128) ? wn[c * 128 + k] : ws[c * 128 + k - 128];
    short hi = f2bf(w);
    __hip_bfloat16 hb = *(__hip_bfloat16*)&hi;
    float hif = __bfloat162float(hb);
    whi[i] = hi;
    wlo[i] = f2bf(w - hif);
}

// layer 2 (commuted): [128 c][128 k], c<64 -> Wn2 rows (tn), c>=64 -> Ws2 rows (ts)
__global__ void k_wprep2(const float* __restrict__ wn, const float* __restrict__ ws,
                         short* __restrict__ whi, short* __restrict__ wlo) {
    int i = blockIdx.x * 256 + threadIdx.x;
    if (i >= 128 * 128) return;
    int c = i >> 7, k = i & 127;
    float w = (c < 64) ? wn[c * 128 + k] : ws[(c - 64) * 128 + k];
    short hi = f2bf(w);
    __hip_bfloat16 hb = *(__hip_bfloat16*)&hi;
    float hif = __bfloat162float(hb);
    whi[i] = hi;
    wlo[i] = f2bf(w - hif);
}

// ---------------- pipelined LDS-staged MFMA transform ----------------
// 8 waves; wave owns 16 output cols (B hi+lo in regs). A tile (16 rows) staged
// in XOR-swizzled LDS, double-buffered, loads issued one iteration ahead.
// KH=2: A=[mean|h], K=256. KH=1: A=h, K=128 (layer-2 commuted, HALFBIAS).

template <int KH, bool RELU, bool HALFBIAS, int CHUNK>
__global__ __launch_bounds__(512) void k_transform2(
    const ushort* __restrict__ meanbuf, const ushort* __restrict__ hbuf,
    const bf16x8* __restrict__ whi, const bf16x8* __restrict__ wlo,
    const float* __restrict__ bias, ushort* __restrict__ out, int n, int nTiles) {
    constexpr int ROWB = KH * 256;  // LDS bytes per row
    constexpr int KS = KH * 4;
    __shared__ ushort lds[2][16 * KH * 128];

    const int t = threadIdx.x;
    const int wave = t >> 6, lane = t & 63;
    const int lmod = lane & 15, lgrp = lane >> 4;
    const int c = wave * 16 + lmod;

    bf16x8 bh[KS], bl[KS];
#pragma unroll
    for (int ks = 0; ks < KS; ++ks) {
        int idx = c * (KH * 16) + ks * 4 + lgrp;
        bh[ks] = whi[idx];
        bl[ks] = wlo[idx];
    }
    float bv;
    if (HALFBIAS) bv = (c >= 64) ? bias[c - 64] : 0.f;
    else bv = bias[c];

    const int srow = t >> 5;  // 0..15
    const int seg = t & 31;   // 0..31
    const int tile0 = blockIdx.x * CHUNK;
    if (tile0 >= nTiles) return;
    const int nt = (nTiles - tile0 < CHUNK) ? (nTiles - tile0) : CHUNK;
    const int swr = (srow * ROWB + seg * (KH == 2 ? 16 : 8)) ^ ((srow & 7) << 4);

    uint4 R;
    // prologue: load tile0, write buf0, load tile1
    {
        int m = tile0 * 16 + srow; if (m >= n) m = n - 1;
        if constexpr (KH == 2) {
            const ushort* sp = (seg < 16) ? (meanbuf + (size_t)m * 128 + seg * 8)
                                          : (hbuf + (size_t)m * 128 + (seg - 16) * 8);
            R = *(const uint4*)sp;
        } else {
            uint2 r2 = *(const uint2*)(hbuf + (size_t)m * 128 + seg * 4);
            R.x = r2.x; R.y = r2.y;
        }
    }
    if constexpr (KH == 2) *(uint4*)((char*)lds[0] + swr) = R;
    else { uint2 r2; r2.x = R.x; r2.y = R.y; *(uint2*)((char*)lds[0] + swr) = r2; }
    {
        int m = (tile0 + 1) * 16 + srow; if (m >= n) m = n - 1;
        if constexpr (KH == 2) {
            const ushort* sp = (seg < 16) ? (meanbuf + (size_t)m * 128 + seg * 8)
                                          : (hbuf + (size_t)m * 128 + (seg - 16) * 8);
            R = *(const uint4*)sp;
        } else {
            uint2 r2 = *(const uint2*)(hbuf + (size_t)m * 128 + seg * 4);
            R.x = r2.x; R.y = r2.y;
        }
    }

    for (int tt = 0; tt < nt; ++tt) {
        __syncthreads();  // buf[tt&1] ready for all waves
        if (tt + 1 < nt) {  // write next tile (other buffer)
            if constexpr (KH == 2) *(uint4*)((char*)lds[(tt + 1) & 1] + swr) = R;
            else { uint2 r2; r2.x = R.x; r2.y = R.y; *(uint2*)((char*)lds[(tt + 1) & 1] + swr) = r2; }
        }
        if (tt + 2 < nt) {  // issue load for tile tt+2 (consumed next iter)
            int m = (tile0 + tt + 2) * 16 + srow; if (m >= n) m = n - 1;
            if constexpr (KH == 2) {
                const ushort* sp = (seg < 16) ? (meanbuf + (size_t)m * 128 + seg * 8)
                                              : (hbuf + (size_t)m * 128 + (seg - 16) * 8);
                R = *(const uint4*)sp;
            } else {
                uint2 r2 = *(const uint2*)(hbuf + (size_t)m * 128 + seg * 4);
                R.x = r2.x; R.y = r2.y;
            }
        }

        bf16x8 af[KS];
#pragma unroll
        for (int ks = 0; ks < KS; ++ks) {
            int byte = (lmod * ROWB + ks * 64 + lgrp * 16) ^ ((lmod & 7) << 4);
            af[ks] = *(const bf16x8*)((const char*)lds[tt & 1] + byte);
        }
        f32x4 ah = {0.f, 0.f, 0.f, 0.f}, al = {0.f, 0.f, 0.f, 0.f};
#pragma unroll
        for (int ks = 0; ks < KS; ++ks) {
            ah = __builtin_amdgcn_mfma_f32_16x16x32_bf16(af[ks], bh[ks], ah, 0, 0, 0);
            al = __builtin_amdgcn_mfma_f32_16x16x32_bf16(af[ks], bl[ks], al, 0, 0, 0);
        }
        int row0 = (tile0 + tt) * 16;
#pragma unroll
        for (int r = 0; r < 4; ++r) {
            int rr = row0 + lgrp * 4 + r;
            float v = ah[r] + al[r] + bv;
            if (RELU) v = fmaxf(v, 0.f);
            if (rr < n) out[(size_t)rr * 128 + c] = (ushort)f2bf(v);
        }
    }
}

// ---------------- pool ----------------

__global__ void k_gbounds(const int* __restrict__ batch, int* __restrict__ gstart, int n) {
    int g = blockIdx.x * blockDim.x + threadIdx.x;
    if (g > NGRAPHS) return;
    int lo = 0, hi = n;
    while (lo < hi) {
        int mid = (lo + hi) >> 1;
        if (batch[mid] < g) lo = mid + 1; else hi = mid;
    }
    gstart[g] = lo;
}

__global__ __launch_bounds__(256) void k_pool2(const ushort* __restrict__ h,
                                               const int* __restrict__ gstart,
                                               float* __restrict__ out) {
    int g = blockIdx.x;
    int t = threadIdx.x, lane = t & 63, wv = t >> 6;
    int s = gstart[g], e = gstart[g + 1];
    float acc = 0.f;
    for (int i = s + wv; i < e; i += 4) {
        uint v = h[(size_t)i * 64 + lane];
        acc += __uint_as_float(v << 16);
    }
    __shared__ float red[4][64];
    red[wv][lane] = acc;
    __syncthreads();
    if (wv == 0) {
        float tot = red[0][lane] + red[1][lane] + red[2][lane] + red[3][lane];
        float c = (float)(e - s);
        out[g * 64 + lane] = tot / fmaxf(c, 1.0f);
    }
}

// ---------------- launcher ----------------

extern "C" void kernel_launch(void* const* d_in, const int* in_sizes, int n_in,
                              void* d_out, int out_size, void* d_ws, size_t ws_size,
                              hipStream_t stream) {
    const float* x = (const float*)d_in[0];
    const int* ei = (const int*)d_in[1];
    const int* batch = (const int*)d_in[2];
    const float* wn0 = (const float*)d_in[3];
    const float* ws0 = (const float*)d_in[4];
    const float* b0 = (const float*)d_in[5];
    const float* wn1 = (const float*)d_in[6];
    const float* ws1 = (const float*)d_in[7];
    const float* b1 = (const float*)d_in[8];
    const float* wn2 = (const float*)d_in[9];
    const float* ws2 = (const float*)d_in[10];
    const float* b2 = (const float*)d_in[11];

    const int n = in_sizes[0] / 128;  // 100000
    const int nE = in_sizes[1] / 2;   // 1600000
    const int* src = ei;
    const int* dst = ei + nE;
    const int NB = (n + 255) >> 8;    // 391 buckets

    char* p = (char*)d_ws;
    auto alloc = [&](size_t bytes) {
        void* r = (void*)p;
        p += (bytes + 255) & ~(size_t)255;
        return r;
    };
    int* bcur = (int*)alloc((size_t)NB * 4);
    uint* pairs = (uint*)alloc((size_t)NB * BCAP * 4);
    int* col = (int*)alloc((size_t)NB * BCAP * 4);
    int* row_start = (int*)alloc((size_t)NB * 256 * 4);
    int* row_end = (int*)alloc((size_t)NB * 256 * 4);
    float* rdeg = (float*)alloc((size_t)NB * 256 * 4);
    int* gstart = (int*)alloc((size_t)(NGRAPHS + 1) * 4);
    short* whi0 = (short*)alloc(128 * 256 * 2);
    short* wlo0 = (short*)alloc(128 * 256 * 2);
    short* whi1 = (short*)alloc(128 * 256 * 2);
    short* wlo1 = (short*)alloc(128 * 256 * 2);
    short* whi2 = (short*)alloc(128 * 128 * 2);
    short* wlo2 = (short*)alloc(128 * 128 * 2);
    ushort* xb = (ushort*)alloc((size_t)n * 128 * 2);
    ushort* meanb = (ushort*)alloc((size_t)n * 128 * 2);  // also reused as t2
    ushort* h1 = (ushort*)alloc((size_t)n * 128 * 2);
    ushort* h2 = (ushort*)alloc((size_t)n * 128 * 2);
    ushort* h3 = (ushort*)alloc((size_t)n * 64 * 2);

    (void)hipMemsetAsync(bcur, 0, (size_t)NB * 4, stream);

    const int tb = 256;

    k_bscatter<<<(nE + 4095) / 4096, tb, 0, stream>>>(src, dst, bcur, pairs, nE, NB);
    k_bbuild<<<NB, tb, 0, stream>>>(bcur, pairs, row_start, row_end, rdeg, col, n);

    k_cast<<<((n * 128 / 4) + 255) / 256, 256, 0, stream>>>(x, xb, n * 128 / 4);

    k_wprep<<<(128 * 256 + 255) / 256, 256, 0, stream>>>(wn0, ws0, whi0, wlo0, 128);
    k_wprep<<<(128 * 256 + 255) / 256, 256, 0, stream>>>(wn1, ws1, whi1, wlo1, 128);
    k_wprep2<<<(128 * 128 + 255) / 256, 256, 0, stream>>>(wn2, ws2, whi2, wlo2);

    k_gbounds<<<3, 256, 0, stream>>>(batch, gstart, n);

    const int aggGrid = ((n * 64) + tb - 1) / tb;
    const int nTiles = (n + 15) / 16;       // 6250
    const int tGrid = (nTiles + 3) / 4;     // CHUNK=4

    // layer 0: agg(xb)->meanb ; T([meanb|xb]) -> h1
    k_agg<<<aggGrid, tb, 0, stream>>>(xb, row_start, row_end, col, rdeg, meanb, n);
    k_transform2<2, true, false, 4><<<tGrid, 512, 0, stream>>>(
        meanb, xb, (const bf16x8*)whi0, (const bf16x8*)wlo0, b0, h1, n, nTiles);
    // layer 1
    k_agg<<<aggGrid, tb, 0, stream>>>(h1, row_start, row_end, col, rdeg, meanb, n);
    k_transform2<2, true, false, 4><<<tGrid, 512, 0, stream>>>(
        meanb, h1, (const bf16x8*)whi1, (const bf16x8*)wlo1, b1, h2, n, nTiles);
    // layer 2 (commuted): t2 = h2 @ [Wn2;Ws2]^T (+b on ts half) -> meanb; then agg2
    k_transform2<1, false, true, 4><<<tGrid, 512, 0, stream>>>(
        h2, h2, (const bf16x8*)whi2, (const bf16x8*)wlo2, b2, meanb, n, nTiles);
    k_agg2<<<aggGrid, tb, 0, stream>>>(meanb, row_start, row_end, col, rdeg, h3, n);

    // pool -> d_out
    k_pool2<<<NGRAPHS, 256, 0, stream>>>(h3, gstart, (float*)d_out);
}

// Round 8
// 324.786 us; speedup vs baseline: 3.9496x; 1.1070x over previous
//
#include <hip/hip_runtime.h>
#include <hip/hip_bf16.h>

#define NGRAPHS 512
#define BCAP 8192

typedef __attribute__((ext_vector_type(8))) short bf16x8;
typedef __attribute__((ext_vector_type(4))) float f32x4;

__device__ inline short f2bf(float x) {
    __hip_bfloat16 h = __float2bfloat16(x);
    return *(short*)&h;
}
__device__ inline float bflo(uint v) { return __uint_as_float(v << 16); }
__device__ inline float bfhi(uint v) { return __uint_as_float(v & 0xffff0000u); }

// ---------------- bucket-sort CSR build ----------------

__global__ __launch_bounds__(256) void k_bscatter(const int* __restrict__ src,
                                                  const int* __restrict__ dst,
                                                  int* __restrict__ bcur,
                                                  uint* __restrict__ pairs,
                                                  int nE, int NB) {
    __shared__ int cnt[512];
    __shared__ int gbase[512];
    const int t = threadIdx.x;
    const int seg0 = blockIdx.x * 4096;

    for (int l = t; l < NB; l += 256) cnt[l] = 0;
    __syncthreads();

    int sv[16], bv[16], rv[16];
#pragma unroll
    for (int k = 0; k < 16; ++k) {
        int e = seg0 + k * 256 + t;
        if (e < nE) {
            int d = dst[e];
            bv[k] = d >> 8;
            rv[k] = atomicAdd(&cnt[bv[k]], 1);
            sv[k] = src[e] | ((d & 255) << 20);
        } else {
            bv[k] = -1;
        }
    }
    __syncthreads();
    for (int l = t; l < NB; l += 256) {
        int c = cnt[l];
        gbase[l] = (c > 0) ? atomicAdd(&bcur[l], c) : 0;
    }
    __syncthreads();
#pragma unroll
    for (int k = 0; k < 16; ++k) {
        if (bv[k] >= 0) {
            int pos = gbase[bv[k]] + rv[k];
            if (pos < BCAP) pairs[(size_t)bv[k] * BCAP + pos] = (uint)sv[k];
        }
    }
}

__global__ __launch_bounds__(256) void k_bbuild(const int* __restrict__ bcur,
                                                const uint* __restrict__ pairs,
                                                int* __restrict__ row_start,
                                                int* __restrict__ row_end,
                                                float* __restrict__ rdeg,
                                                int* __restrict__ col, int n) {
    __shared__ int s[256];
    __shared__ int cur[256];
    const int b = blockIdx.x;
    const int t = threadIdx.x;
    const uint* bp = pairs + (size_t)b * BCAP;
    int cnt = bcur[b];
    if (cnt > BCAP) cnt = BCAP;

    s[t] = 0;
    __syncthreads();
    for (int i = t; i < cnt; i += 256) {
        int local = bp[i] >> 20;
        atomicAdd(&s[local], 1);
    }
    __syncthreads();
    int my = s[t];
    for (int off = 1; off < 256; off <<= 1) {
        int v = (t >= off) ? s[t - off] : 0;
        __syncthreads();
        s[t] += v;
        __syncthreads();
    }
    int excl = s[t] - my;
    int v = b * 256 + t;
    if (v < n) {
        row_start[v] = b * BCAP + excl;
        row_end[v] = b * BCAP + excl + my;
        rdeg[v] = 1.0f / (float)(my > 1 ? my : 1);
    }
    cur[t] = excl;
    __syncthreads();
    for (int i = t; i < cnt; i += 256) {
        uint u = bp[i];
        int local = u >> 20;
        int pos = atomicAdd(&cur[local], 1);
        col[(size_t)b * BCAP + pos] = (int)(u & 0xFFFFFu);
    }
}

// ---------------- f32 -> bf16 cast ----------------

__global__ __launch_bounds__(256) void k_cast(const float* __restrict__ x,
                                              ushort* __restrict__ xb, int total4) {
    int i = blockIdx.x * 256 + threadIdx.x;
    if (i >= total4) return;
    float4 v = ((const float4*)x)[i];
    ushort4 o;
    o.x = (ushort)f2bf(v.x);
    o.y = (ushort)f2bf(v.y);
    o.z = (ushort)f2bf(v.z);
    o.w = (ushort)f2bf(v.w);
    ((ushort4*)xb)[i] = o;
}

// ---------------- mean aggregation (128 ch) ----------------

__global__ __launch_bounds__(256) void k_agg(const ushort* __restrict__ h,
                                             const int* __restrict__ row_start,
                                             const int* __restrict__ row_end,
                                             const int* __restrict__ col,
                                             const float* __restrict__ rdeg,
                                             ushort* __restrict__ out, int n) {
    int w = (blockIdx.x * blockDim.x + threadIdx.x) >> 6;
    int lane = threadIdx.x & 63;
    if (w >= n) return;
    int s = row_start[w], e = row_end[w];
    int grp = lane >> 4;
    int cl = lane & 15;

    float a0 = 0.f, a1 = 0.f, a2 = 0.f, a3 = 0.f, a4 = 0.f, a5 = 0.f, a6 = 0.f, a7 = 0.f;

    if (e > s) {
        int cfirst = col[s];
        for (int j = s; j < e; j += 8) {
            int j0 = j + grp, j1 = j + 4 + grp;
            bool ok0 = j0 < e, ok1 = j1 < e;
            int c0 = ok0 ? col[j0] : cfirst;
            int c1 = ok1 ? col[j1] : cfirst;
            uint4 r0 = *(const uint4*)(h + (size_t)c0 * 128 + cl * 8);
            uint4 r1 = *(const uint4*)(h + (size_t)c1 * 128 + cl * 8);
            if (ok0) {
                a0 += bflo(r0.x); a1 += bfhi(r0.x);
                a2 += bflo(r0.y); a3 += bfhi(r0.y);
                a4 += bflo(r0.z); a5 += bfhi(r0.z);
                a6 += bflo(r0.w); a7 += bfhi(r0.w);
            }
            if (ok1) {
                a0 += bflo(r1.x); a1 += bfhi(r1.x);
                a2 += bflo(r1.y); a3 += bfhi(r1.y);
                a4 += bflo(r1.z); a5 += bfhi(r1.z);
                a6 += bflo(r1.w); a7 += bfhi(r1.w);
            }
        }
        a0 += __shfl_xor(a0, 16); a1 += __shfl_xor(a1, 16);
        a2 += __shfl_xor(a2, 16); a3 += __shfl_xor(a3, 16);
        a4 += __shfl_xor(a4, 16); a5 += __shfl_xor(a5, 16);
        a6 += __shfl_xor(a6, 16); a7 += __shfl_xor(a7, 16);
        a0 += __shfl_xor(a0, 32); a1 += __shfl_xor(a1, 32);
        a2 += __shfl_xor(a2, 32); a3 += __shfl_xor(a3, 32);
        a4 += __shfl_xor(a4, 32); a5 += __shfl_xor(a5, 32);
        a6 += __shfl_xor(a6, 32); a7 += __shfl_xor(a7, 32);
    }

    if (grp == 0) {
        float r = rdeg[w];
        uint4 o;
        o.x = (uint)(ushort)f2bf(a0 * r) | ((uint)(ushort)f2bf(a1 * r) << 16);
        o.y = (uint)(ushort)f2bf(a2 * r) | ((uint)(ushort)f2bf(a3 * r) << 16);
        o.z = (uint)(ushort)f2bf(a4 * r) | ((uint)(ushort)f2bf(a5 * r) << 16);
        o.w = (uint)(ushort)f2bf(a6 * r) | ((uint)(ushort)f2bf(a7 * r) << 16);
        *(uint4*)(out + (size_t)w * 128 + cl * 8) = o;
    }
}

// ---------------- layer-2 aggregation on t2 = [tn|ts] ----------------

__global__ __launch_bounds__(256) void k_agg2(const ushort* __restrict__ t2,
                                              const int* __restrict__ row_start,
                                              const int* __restrict__ row_end,
                                              const int* __restrict__ col,
                                              const float* __restrict__ rdeg,
                                              ushort* __restrict__ out, int n) {
    int w = (blockIdx.x * blockDim.x + threadIdx.x) >> 6;
    int lane = threadIdx.x & 63;
    if (w >= n) return;
    int s = row_start[w], e = row_end[w];
    int grp = lane >> 4;
    int cl = lane & 15;

    float a0 = 0.f, a1 = 0.f, a2 = 0.f, a3 = 0.f;

    if (e > s) {
        int cfirst = col[s];
        for (int j = s; j < e; j += 8) {
            int j0 = j + grp, j1 = j + 4 + grp;
            bool ok0 = j0 < e, ok1 = j1 < e;
            int c0 = ok0 ? col[j0] : cfirst;
            int c1 = ok1 ? col[j1] : cfirst;
            uint2 r0 = *(const uint2*)(t2 + (size_t)c0 * 128 + cl * 4);
            uint2 r1 = *(const uint2*)(t2 + (size_t)c1 * 128 + cl * 4);
            if (ok0) {
                a0 += bflo(r0.x); a1 += bfhi(r0.x);
                a2 += bflo(r0.y); a3 += bfhi(r0.y);
            }
            if (ok1) {
                a0 += bflo(r1.x); a1 += bfhi(r1.x);
                a2 += bflo(r1.y); a3 += bfhi(r1.y);
            }
        }
        a0 += __shfl_xor(a0, 16); a1 += __shfl_xor(a1, 16);
        a2 += __shfl_xor(a2, 16); a3 += __shfl_xor(a3, 16);
        a0 += __shfl_xor(a0, 32); a1 += __shfl_xor(a1, 32);
        a2 += __shfl_xor(a2, 32); a3 += __shfl_xor(a3, 32);
    }

    if (grp == 0) {
        float r = rdeg[w];
        uint2 tsv = *(const uint2*)(t2 + (size_t)w * 128 + 64 + cl * 4);
        float t0 = bflo(tsv.x), t1 = bfhi(tsv.x);
        float t2v = bflo(tsv.y), t3 = bfhi(tsv.y);
        uint2 o;
        o.x = (uint)(ushort)f2bf(a0 * r + t0) | ((uint)(ushort)f2bf(a1 * r + t1) << 16);
        o.y = (uint)(ushort)f2bf(a2 * r + t2v) | ((uint)(ushort)f2bf(a3 * r + t3) << 16);
        *(uint2*)(out + (size_t)w * 64 + cl * 4) = o;
    }
}

// ---------------- weight prep ----------------

__global__ void k_wprep(const float* __restrict__ wn, const float* __restrict__ ws,
                        short* __restrict__ whi, short* __restrict__ wlo, int outc) {
    int i = blockIdx.x * 256 + threadIdx.x;
    if (i >= outc * 256) return;
    int c = i >> 8, k = i & 255;
    float w = (k < 128) ? wn[c * 128 + k] : ws[c * 128 + k - 128];
    short hi = f2bf(w);
    __hip_bfloat16 hb = *(__hip_bfloat16*)&hi;
    float hif = __bfloat162float(hb);
    whi[i] = hi;
    wlo[i] = f2bf(w - hif);
}

__global__ void k_wprep2(const float* __restrict__ wn, const float* __restrict__ ws,
                         short* __restrict__ whi, short* __restrict__ wlo) {
    int i = blockIdx.x * 256 + threadIdx.x;
    if (i >= 128 * 128) return;
    int c = i >> 7, k = i & 127;
    float w = (c < 64) ? wn[c * 128 + k] : ws[(c - 64) * 128 + k];
    short hi = f2bf(w);
    __hip_bfloat16 hb = *(__hip_bfloat16*)&hi;
    float hif = __bfloat162float(hb);
    whi[i] = hi;
    wlo[i] = f2bf(w - hif);
}

// ---------------- pipelined LDS-staged MFMA transform ----------------
// CHUNK=13: per-block B-fragment load (128KB for KH=2) amortized over 208 rows.

template <int KH, bool RELU, bool HALFBIAS, int CHUNK>
__global__ __launch_bounds__(512) void k_transform2(
    const ushort* __restrict__ meanbuf, const ushort* __restrict__ hbuf,
    const bf16x8* __restrict__ whi, const bf16x8* __restrict__ wlo,
    const float* __restrict__ bias, ushort* __restrict__ out, int n, int nTiles) {
    constexpr int ROWB = KH * 256;
    constexpr int KS = KH * 4;
    __shared__ ushort lds[2][16 * KH * 128];

    const int t = threadIdx.x;
    const int wave = t >> 6, lane = t & 63;
    const int lmod = lane & 15, lgrp = lane >> 4;
    const int c = wave * 16 + lmod;

    bf16x8 bh[KS], bl[KS];
#pragma unroll
    for (int ks = 0; ks < KS; ++ks) {
        int idx = c * (KH * 16) + ks * 4 + lgrp;
        bh[ks] = whi[idx];
        bl[ks] = wlo[idx];
    }
    float bv;
    if (HALFBIAS) bv = (c >= 64) ? bias[c - 64] : 0.f;
    else bv = bias[c];

    const int srow = t >> 5;
    const int seg = t & 31;
    const int tile0 = blockIdx.x * CHUNK;
    if (tile0 >= nTiles) return;
    const int nt = (nTiles - tile0 < CHUNK) ? (nTiles - tile0) : CHUNK;
    const int swr = (srow * ROWB + seg * (KH == 2 ? 16 : 8)) ^ ((srow & 7) << 4);

    uint4 R;
    {
        int m = tile0 * 16 + srow; if (m >= n) m = n - 1;
        if constexpr (KH == 2) {
            const ushort* sp = (seg < 16) ? (meanbuf + (size_t)m * 128 + seg * 8)
                                          : (hbuf + (size_t)m * 128 + (seg - 16) * 8);
            R = *(const uint4*)sp;
        } else {
            uint2 r2 = *(const uint2*)(hbuf + (size_t)m * 128 + seg * 4);
            R.x = r2.x; R.y = r2.y;
        }
    }
    if constexpr (KH == 2) *(uint4*)((char*)lds[0] + swr) = R;
    else { uint2 r2; r2.x = R.x; r2.y = R.y; *(uint2*)((char*)lds[0] + swr) = r2; }
    {
        int m = (tile0 + 1) * 16 + srow; if (m >= n) m = n - 1;
        if constexpr (KH == 2) {
            const ushort* sp = (seg < 16) ? (meanbuf + (size_t)m * 128 + seg * 8)
                                          : (hbuf + (size_t)m * 128 + (seg - 16) * 8);
            R = *(const uint4*)sp;
        } else {
            uint2 r2 = *(const uint2*)(hbuf + (size_t)m * 128 + seg * 4);
            R.x = r2.x; R.y = r2.y;
        }
    }

    for (int tt = 0; tt < nt; ++tt) {
        __syncthreads();
        if (tt + 1 < nt) {
            if constexpr (KH == 2) *(uint4*)((char*)lds[(tt + 1) & 1] + swr) = R;
            else { uint2 r2; r2.x = R.x; r2.y = R.y; *(uint2*)((char*)lds[(tt + 1) & 1] + swr) = r2; }
        }
        if (tt + 2 < nt) {
            int m = (tile0 + tt + 2) * 16 + srow; if (m >= n) m = n - 1;
            if constexpr (KH == 2) {
                const ushort* sp = (seg < 16) ? (meanbuf + (size_t)m * 128 + seg * 8)
                                              : (hbuf + (size_t)m * 128 + (seg - 16) * 8);
                R = *(const uint4*)sp;
            } else {
                uint2 r2 = *(const uint2*)(hbuf + (size_t)m * 128 + seg * 4);
                R.x = r2.x; R.y = r2.y;
            }
        }

        bf16x8 af[KS];
#pragma unroll
        for (int ks = 0; ks < KS; ++ks) {
            int byte = (lmod * ROWB + ks * 64 + lgrp * 16) ^ ((lmod & 7) << 4);
            af[ks] = *(const bf16x8*)((const char*)lds[tt & 1] + byte);
        }
        f32x4 ah = {0.f, 0.f, 0.f, 0.f}, al = {0.f, 0.f, 0.f, 0.f};
#pragma unroll
        for (int ks = 0; ks < KS; ++ks) {
            ah = __builtin_amdgcn_mfma_f32_16x16x32_bf16(af[ks], bh[ks], ah, 0, 0, 0);
            al = __builtin_amdgcn_mfma_f32_16x16x32_bf16(af[ks], bl[ks], al, 0, 0, 0);
        }
        int row0 = (tile0 + tt) * 16;
#pragma unroll
        for (int r = 0; r < 4; ++r) {
            int rr = row0 + lgrp * 4 + r;
            float v = ah[r] + al[r] + bv;
            if (RELU) v = fmaxf(v, 0.f);
            if (rr < n) out[(size_t)rr * 128 + c] = (ushort)f2bf(v);
        }
    }
}

// ---------------- pool ----------------

__global__ void k_gbounds(const int* __restrict__ batch, int* __restrict__ gstart, int n) {
    int g = blockIdx.x * blockDim.x + threadIdx.x;
    if (g > NGRAPHS) return;
    int lo = 0, hi = n;
    while (lo < hi) {
        int mid = (lo + hi) >> 1;
        if (batch[mid] < g) lo = mid + 1; else hi = mid;
    }
    gstart[g] = lo;
}

__global__ __launch_bounds__(256) void k_pool2(const ushort* __restrict__ h,
                                               const int* __restrict__ gstart,
                                               float* __restrict__ out) {
    int g = blockIdx.x;
    int t = threadIdx.x, lane = t & 63, wv = t >> 6;
    int s = gstart[g], e = gstart[g + 1];
    float acc = 0.f;
    for (int i = s + wv; i < e; i += 4) {
        uint v = h[(size_t)i * 64 + lane];
        acc += __uint_as_float(v << 16);
    }
    __shared__ float red[4][64];
    red[wv][lane] = acc;
    __syncthreads();
    if (wv == 0) {
        float tot = red[0][lane] + red[1][lane] + red[2][lane] + red[3][lane];
        float c = (float)(e - s);
        out[g * 64 + lane] = tot / fmaxf(c, 1.0f);
    }
}

// ---------------- launcher ----------------

extern "C" void kernel_launch(void* const* d_in, const int* in_sizes, int n_in,
                              void* d_out, int out_size, void* d_ws, size_t ws_size,
                              hipStream_t stream) {
    const float* x = (const float*)d_in[0];
    const int* ei = (const int*)d_in[1];
    const int* batch = (const int*)d_in[2];
    const float* wn0 = (const float*)d_in[3];
    const float* ws0 = (const float*)d_in[4];
    const float* b0 = (const float*)d_in[5];
    const float* wn1 = (const float*)d_in[6];
    const float* ws1 = (const float*)d_in[7];
    const float* b1 = (const float*)d_in[8];
    const float* wn2 = (const float*)d_in[9];
    const float* ws2 = (const float*)d_in[10];
    const float* b2 = (const float*)d_in[11];

    const int n = in_sizes[0] / 128;  // 100000
    const int nE = in_sizes[1] / 2;   // 1600000
    const int* src = ei;
    const int* dst = ei + nE;
    const int NB = (n + 255) >> 8;    // 391 buckets

    char* p = (char*)d_ws;
    auto alloc = [&](size_t bytes) {
        void* r = (void*)p;
        p += (bytes + 255) & ~(size_t)255;
        return r;
    };
    int* bcur = (int*)alloc((size_t)NB * 4);
    uint* pairs = (uint*)alloc((size_t)NB * BCAP * 4);
    int* col = (int*)alloc((size_t)NB * BCAP * 4);
    int* row_start = (int*)alloc((size_t)NB * 256 * 4);
    int* row_end = (int*)alloc((size_t)NB * 256 * 4);
    float* rdeg = (float*)alloc((size_t)NB * 256 * 4);
    int* gstart = (int*)alloc((size_t)(NGRAPHS + 1) * 4);
    short* whi0 = (short*)alloc(128 * 256 * 2);
    short* wlo0 = (short*)alloc(128 * 256 * 2);
    short* whi1 = (short*)alloc(128 * 256 * 2);
    short* wlo1 = (short*)alloc(128 * 256 * 2);
    short* whi2 = (short*)alloc(128 * 128 * 2);
    short* wlo2 = (short*)alloc(128 * 128 * 2);
    ushort* xb = (ushort*)alloc((size_t)n * 128 * 2);
    ushort* meanb = (ushort*)alloc((size_t)n * 128 * 2);  // also reused as t2
    ushort* h1 = (ushort*)alloc((size_t)n * 128 * 2);
    ushort* h2 = (ushort*)alloc((size_t)n * 128 * 2);
    ushort* h3 = (ushort*)alloc((size_t)n * 64 * 2);

    (void)hipMemsetAsync(bcur, 0, (size_t)NB * 4, stream);

    const int tb = 256;

    k_bscatter<<<(nE + 4095) / 4096, tb, 0, stream>>>(src, dst, bcur, pairs, nE, NB);
    k_bbuild<<<NB, tb, 0, stream>>>(bcur, pairs, row_start, row_end, rdeg, col, n);

    k_cast<<<((n * 128 / 4) + 255) / 256, 256, 0, stream>>>(x, xb, n * 128 / 4);

    k_wprep<<<(128 * 256 + 255) / 256, 256, 0, stream>>>(wn0, ws0, whi0, wlo0, 128);
    k_wprep<<<(128 * 256 + 255) / 256, 256, 0, stream>>>(wn1, ws1, whi1, wlo1, 128);
    k_wprep2<<<(128 * 128 + 255) / 256, 256, 0, stream>>>(wn2, ws2, whi2, wlo2);

    k_gbounds<<<3, 256, 0, stream>>>(batch, gstart, n);

    const int aggGrid = ((n * 64) + tb - 1) / tb;
    const int nTiles = (n + 15) / 16;         // 6250
    const int CH = 13;                        // B-load amortization (481 blocks)
    const int tGrid = (nTiles + CH - 1) / CH;

    // layer 0
    k_agg<<<aggGrid, tb, 0, stream>>>(xb, row_start, row_end, col, rdeg, meanb, n);
    k_transform2<2, true, false, 13><<<tGrid, 512, 0, stream>>>(
        meanb, xb, (const bf16x8*)whi0, (const bf16x8*)wlo0, b0, h1, n, nTiles);
    // layer 1
    k_agg<<<aggGrid, tb, 0, stream>>>(h1, row_start, row_end, col, rdeg, meanb, n);
    k_transform2<2, true, false, 13><<<tGrid, 512, 0, stream>>>(
        meanb, h1, (const bf16x8*)whi1, (const bf16x8*)wlo1, b1, h2, n, nTiles);
    // layer 2 (commuted)
    k_transform2<1, false, true, 13><<<tGrid, 512, 0, stream>>>(
        h2, h2, (const bf16x8*)whi2, (const bf16x8*)wlo2, b2, meanb, n, nTiles);
    k_agg2<<<aggGrid, tb, 0, stream>>>(meanb, row_start, row_end, col, rdeg, h3, n);

    // pool -> d_out
    k_pool2<<<NGRAPHS, 256, 0, stream>>>(h3, gstart, (float*)d_out);
}